// Round 5
// baseline (92.345 us; speedup 1.0000x reference)
//
#include <hip/hip_runtime.h>
#include <math.h>

// out[b,s,n] = sum_e SIN_TABLE[idx(w[e,n]*x[b,s,e] + b[e,n] + t[s])]
// B=2, S=1024, E=128, N=512, LUT_RES=512.
//
// Round-4 structure: e-split into EC=4 chunks so occupancy (waves/SIMD) and
// per-thread row-amortization (ST) decouple. Main kernel: 2048 blocks x 256
// (8 waves/SIMD), each computes a partial sum over 32 e's for 8 rows x 256 n.
// Partials (4 x 2048 x 512 fp32 = 16 MB, L2-resident) in d_ws; reducer sums 4.
//
// Bin-unit math per element: u = fma(wn, x, btn); k = floorf(u);
// acc += v_sin(k/512)  (v_sin takes revolutions, periodicity == %512,
// |arg| <= ~165 < 256 valid range).

constexpr int E_DIM = 128;
constexpr int N_DIM = 512;
constexpr int ST    = 8;     // s-rows per block
constexpr int TPB   = 256;   // threads per block (n-half)
constexpr int EC    = 4;     // e-chunks
constexpr int ECH   = E_DIM / EC;   // 32 e's per chunk

__global__ __launch_bounds__(TPB) void sin_layer_partial(
    const float* __restrict__ x,    // (B,S,E)
    const float* __restrict__ w,    // (E,N)
    const float* __restrict__ bv_,  // (E,N)
    const float* __restrict__ t,    // (S)
    float* __restrict__ part,       // (EC, B*S, N) partial sums
    int S, int BS)
{
    constexpr float SCALE  = 512.0f * 0.15915493667125702f;  // bins per radian
    constexpr float INV512 = 1.0f / 512.0f;

    const int bid = blockIdx.x;
    const int ec  = bid & (EC - 1);          // e-chunk
    const int nh  = (bid >> 2) & 1;          // n-half
    const int g   = bid >> 3;                // row group
    const int n   = nh * TPB + threadIdx.x;
    const int bs0 = g * ST;
    const int e0  = ec * ECH;

    float tn[ST];                             // wave-uniform
    float acc[ST];
    const float* xr[ST];
#pragma unroll
    for (int i = 0; i < ST; ++i) {
        const int bs = bs0 + i;
        const int s  = (bs >= S) ? (bs - S) : bs;
        tn[i]  = t[s] * SCALE;                // t in bin units
        xr[i]  = x + (size_t)bs * E_DIM + e0;
        acc[i] = 0.0f;
    }

    const float* wp = w   + (size_t)e0 * N_DIM + n;
    const float* bp = bv_ + (size_t)e0 * N_DIM + n;

#pragma unroll 4
    for (int e = 0; e < ECH; ++e) {
        const float wv = wp[(size_t)e * N_DIM];
        const float bb = bp[(size_t)e * N_DIM];
        const float wn = wv * SCALE;          // w in bin units
        float btn[ST];
#pragma unroll
        for (int i = 0; i < ST; ++i)
            btn[i] = __fmaf_rn(bb, SCALE, tn[i]);   // (b + t) in bin units
#pragma unroll
        for (int i = 0; i < ST; ++i) {
            const float xv = xr[i][e];               // wave-uniform
            float u = __fmaf_rn(wn, xv, btn[i]);     // bin-scaled phase
            float k = floorf(u);                     // LUT bin
            acc[i] += __builtin_amdgcn_sinf(k * INV512);
        }
    }

    float* pp = part + (size_t)ec * BS * N_DIM;
#pragma unroll
    for (int i = 0; i < ST; ++i) {
        pp[(size_t)(bs0 + i) * N_DIM + n] = acc[i];
    }
}

__global__ __launch_bounds__(TPB) void sin_layer_reduce(
    const float* __restrict__ part,   // (EC, B*S*N) as float4
    float* __restrict__ out,          // (B*S*N)
    int nvec)                         // B*S*N/4
{
    const int i = blockIdx.x * TPB + threadIdx.x;
    if (i >= nvec) return;
    const float4* p = (const float4*)part;
    float4 a = p[i];
    float4 b = p[i + (size_t)nvec];
    float4 c = p[i + (size_t)2 * nvec];
    float4 d = p[i + (size_t)3 * nvec];
    float4 o;
    o.x = (a.x + b.x) + (c.x + d.x);
    o.y = (a.y + b.y) + (c.y + d.y);
    o.z = (a.z + b.z) + (c.z + d.z);
    o.w = (a.w + b.w) + (c.w + d.w);
    ((float4*)out)[i] = o;
}

extern "C" void kernel_launch(void* const* d_in, const int* in_sizes, int n_in,
                              void* d_out, int out_size, void* d_ws, size_t ws_size,
                              hipStream_t stream) {
    const float* x = (const float*)d_in[0];   // (B,S,E)
    const float* w = (const float*)d_in[1];   // (E,N)
    const float* b = (const float*)d_in[2];   // (E,N)
    const float* t = (const float*)d_in[3];   // (S)
    float* out  = (float*)d_out;              // (B*S*N)
    float* part = (float*)d_ws;               // (EC, B*S, N)

    const int S  = in_sizes[3];               // 1024
    const int BS = in_sizes[0] / E_DIM;       // 2048

    const int grid1 = (BS / ST) * 2 * EC;     // 256*2*4 = 2048 blocks
    sin_layer_partial<<<grid1, TPB, 0, stream>>>(x, w, b, t, part, S, BS);

    const int nvec  = out_size / 4;           // 262144
    const int grid2 = (nvec + TPB - 1) / TPB; // 1024 blocks
    sin_layer_reduce<<<grid2, TPB, 0, stream>>>(part, out, nvec);
}